// Round 16
// baseline (116.852 us; speedup 1.0000x reference)
//
#include <hip/hip_runtime.h>
#include <math.h>

#define IMG_H 512
#define IMG_W 512
#define PSIZE 512
#define NIMG 16
#define NBOX 16
#define Z0 8                        // z-split for j==0 (full-rect) tasks
#define SLOTS 24                    // Z0 + 16 pair slots per (b,i)
#define NTASK (256 * 17 * Z0)       // 34816 pair-task items
#define NCOPY 2048                  // copy chunks
#define CHUNK4 1536                 // float4 per chunk (6/thread @256thr)
#define FBLOCKS 4096

// workspace layout (floats)
#define WS_PMEAN 0                  // 3
#define WS_PSTD  3                  // 3
#define WS_PART  6                  // 256*6
#define WS_PAIR  1544               // [bi][SLOTS][8] = 49152
#define WS_COEF  (1544 + 256 * SLOTS * 8)   // [bi][8]

typedef float f4u __attribute__((ext_vector_type(4), aligned(4)));
typedef float f2u __attribute__((ext_vector_type(2), aligned(4)));

struct BoxGeo { int y0, x0, ph, pw, valid; };

__device__ __forceinline__ BoxGeo make_geo(const float* bx) {
    float ymin = bx[0], xmin = bx[1], ymax = bx[2], xmax = bx[3];
    float h = ymax - ymin, w = xmax - xmin;
    float pwf = h * 0.3f;            // SCALE
    float phf = 1.0f * pwf;          // ASPECT * pw
    float oy = ymin + h * 0.5f;
    float ox = xmin + w * 0.5f;
    float yp = fmaxf(oy - phf * 0.5f, 0.0f);
    float xp = fmaxf(ox - pwf * 0.5f, 0.0f);
    if (yp + phf > (float)IMG_H) yp = (float)IMG_H - phf;
    if (xp + pwf > (float)IMG_W) xp = (float)IMG_W - pwf;
    BoxGeo g;
    g.y0 = (int)yp; g.x0 = (int)xp;   // tf.cast truncation
    g.ph = (int)phf; g.pw = (int)pwf;
    g.valid = (phf > 60.0f) ? 1 : 0;  // MIN_PATCH_H tested on float ph
    return g;
}

// vectorized bilinear: 4 memory requests (dwordx4+dwordx2 per row) not 12.
__device__ __forceinline__ void bsample_fast(const float* __restrict__ patch,
                                             int relY, int relX,
                                             float phf, float pwf, float s[3]) {
    float sy = ((float)relY + 0.5f) * (float)PSIZE / phf - 0.5f;
    sy = fminf(fmaxf(sy, 0.0f), (float)(PSIZE - 1));
    float sx = ((float)relX + 0.5f) * (float)PSIZE / pwf - 0.5f;
    sx = fminf(fmaxf(sx, 0.0f), (float)(PSIZE - 1));
    int y0 = (int)floorf(sy);
    int y1 = min(y0 + 1, PSIZE - 1);
    int x0 = (int)floorf(sx);
    float wy = sy - (float)y0;
    float wx = sx - (float)x0;
    const int baseX = min(x0, PSIZE - 2);
    const bool hi = (x0 == PSIZE - 1);          // then wx == 0
    const float* r0 = patch + (y0 * PSIZE + baseX) * 3;
    const float* r1 = patch + (y1 * PSIZE + baseX) * 3;
    f4u a0 = *(const f4u*)r0; f2u b0 = *(const f2u*)(r0 + 4);
    f4u a1 = *(const f4u*)r1; f2u b1 = *(const f2u*)(r1 + 4);
    float p00, p01, p10, p11, top, bot;
    p00 = hi ? a0.w : a0.x;  p01 = a0.w;
    p10 = hi ? a1.w : a1.x;  p11 = a1.w;
    top = (1.f - wx) * p00 + wx * p01; bot = (1.f - wx) * p10 + wx * p11;
    s[0] = (1.f - wy) * top + wy * bot;
    p00 = hi ? b0.x : a0.y;  p01 = b0.x;
    p10 = hi ? b1.x : a1.y;  p11 = b1.x;
    top = (1.f - wx) * p00 + wx * p01; bot = (1.f - wx) * p10 + wx * p11;
    s[1] = (1.f - wy) * top + wy * bot;
    p00 = hi ? b0.y : a0.z;  p01 = b0.y;
    p10 = hi ? b1.y : a1.z;  p11 = b1.y;
    top = (1.f - wx) * p00 + wx * p01; bot = (1.f - wx) * p10 + wx * p11;
    s[2] = (1.f - wy) * top + wy * bot;
}

template<int N, int NWAVES>
__device__ __forceinline__ void block_reduceN(float v[N]) {
    __shared__ float lds[NWAVES][N];
    const int lane = threadIdx.x & 63;
    const int wave = threadIdx.x >> 6;
    __syncthreads();
#pragma unroll
    for (int k = 0; k < N; ++k) {
#pragma unroll
        for (int off = 32; off > 0; off >>= 1)
            v[k] += __shfl_down(v[k], off, 64);
    }
    if (lane == 0) {
#pragma unroll
        for (int k = 0; k < N; ++k) lds[wave][k] = v[k];
    }
    __syncthreads();
    if (wave == 0) {
#pragma unroll
        for (int k = 0; k < N; ++k) {
            float x = (lane < NWAVES) ? lds[lane][k] : 0.0f;
#pragma unroll
            for (int off = 32; off > 0; off >>= 1)
                x += __shfl_down(x, off, 64);
            if (lane == 0) lds[0][k] = x;
        }
    }
    __syncthreads();
#pragma unroll
    for (int k = 0; k < N; ++k) v[k] = lds[0][k];
}

// ---------------------------------------------------------------------------
// K1: patch mean/std partials
// ---------------------------------------------------------------------------
__global__ void patch_stats_partial(const float* __restrict__ patch,
                                    float* __restrict__ ws) {
    const int g = blockIdx.x * 256 + threadIdx.x;
    const float4* p4 = (const float4*)patch;
    float4 a = p4[3 * g], b = p4[3 * g + 1], c = p4[3 * g + 2];
    float v[6];
    v[0] = a.x + a.w + b.z + c.y;
    v[1] = a.y + b.x + b.w + c.z;
    v[2] = a.z + b.y + c.x + c.w;
    v[3] = a.x*a.x + a.w*a.w + b.z*b.z + c.y*c.y;
    v[4] = a.y*a.y + b.x*b.x + b.w*b.w + c.z*c.z;
    v[5] = a.z*a.z + b.y*b.y + c.x*c.x + c.w*c.w;
    block_reduceN<6, 4>(v);
    if (threadIdx.x == 0) {
        float* o = ws + WS_PART + blockIdx.x * 6;
#pragma unroll
        for (int k = 0; k < 6; ++k) o[k] = v[k];
    }
}

// ---------------------------------------------------------------------------
// K2: fused — grid-stride over [pair tasks | copy chunks | stats-final].
// Pair tasks: item = z*4352 + j_idx*256 + bi. Uniform early exits.
// ---------------------------------------------------------------------------
__launch_bounds__(256)
__global__ void fused(const float* __restrict__ images,
                      const float* __restrict__ boxes,
                      const float* __restrict__ patch,
                      float* __restrict__ ws,
                      float* __restrict__ out) {
    const int tid = threadIdx.x;
    __shared__ BoxGeo geo[NBOX];
    const int total = NTASK + NCOPY + 1;

    for (int it = blockIdx.x; it < total; it += FBLOCKS) {
        if (it >= NTASK) {
            if (it < NTASK + NCOPY) {            // copy chunk
                const int c = it - NTASK;
                const float4* s4 = (const float4*)images;
                float4* d4 = (float4*)out;
                const int base = c * CHUNK4 + tid;
#pragma unroll
                for (int u = 0; u < 6; ++u)
                    d4[base + u * 256] = s4[base + u * 256];
            } else {                             // stats final
                float v[6];
                const float* p = ws + WS_PART + tid * 6;
#pragma unroll
                for (int k = 0; k < 6; ++k) v[k] = p[k];
                block_reduceN<6, 4>(v);
                if (tid == 0) {
                    const float n = (float)(PSIZE * PSIZE);
#pragma unroll
                    for (int c = 0; c < 3; ++c) {
                        float m = v[c] / n;
                        float var = v[3 + c] / n - m * m;
                        ws[WS_PMEAN + c] = m;
                        ws[WS_PSTD + c] = sqrtf(fmaxf(var, 0.f)) + 1e-6f;
                    }
                }
            }
            continue;
        }
        // ---- pair task ----
        const int z = it / (17 * 256);
        const int rem = it % (17 * 256);
        const int j_idx = rem >> 8;
        const int bi = rem & 255;
        const int b = bi >> 4, i = bi & 15;
        if (j_idx > i) continue;                 // slot never read
        if (j_idx >= 1 && z > 0) continue;       // no such slot

        const BoxGeo gi = make_geo(boxes + (b * NBOX + i) * 4);
        if (!gi.valid) continue;                 // solve skips invalid i

        const int slot = (j_idx == 0) ? z : (Z0 + j_idx - 1);
        float* o = ws + WS_PAIR + ((size_t)bi * SLOTS + slot) * 8;

        int ry0 = gi.y0, rx0 = gi.x0;
        int ry1 = gi.y0 + gi.ph, rx1 = gi.x0 + gi.pw;
        int jy0 = 0, jx0 = 0, jph = -1;
        float jphf = 1.f, jpwf = 1.f;
        if (j_idx >= 1) {
            const BoxGeo gj = make_geo(boxes + (b * NBOX + j_idx - 1) * 4);
            if (!gj.valid) {
                if (tid == 0) { for (int k = 0; k < 7; ++k) o[k] = 0.f; }
                continue;
            }
            ry0 = max(ry0, gj.y0); rx0 = max(rx0, gj.x0);
            ry1 = min(ry1, gj.y0 + gj.ph); rx1 = min(rx1, gj.x0 + gj.pw);
            jy0 = gj.y0; jx0 = gj.x0; jph = gj.ph;
            jphf = (float)gj.ph; jpwf = (float)gj.pw;
        }
        const int rw = rx1 - rx0, rh = ry1 - ry0;
        if (rw <= 0 || rh <= 0) {
            if (tid == 0) { for (int k = 0; k < 7; ++k) o[k] = 0.f; }
            continue;
        }

        __syncthreads();                         // guard geo[] reuse
        if (tid < NBOX)
            geo[tid] = make_geo(boxes + (b * NBOX + tid) * 4);
        __syncthreads();

        const int n = rw * rh;
        const float* img = images + (size_t)b * IMG_H * IMG_W * 3;
        const int nz = (j_idx == 0) ? Z0 : 1;

        float v[7] = {0.f, 0.f, 0.f, 0.f, 0.f, 0.f, 0.f};
        for (int t = z * 256 + tid; t < n; t += 256 * nz) {
            const int y = ry0 + t / rw;
            const int x = rx0 + t % rw;
            bool inc = true;
            for (int k = j_idx; k < i; ++k) {    // k = j+1 .. i-1
                const BoxGeo gk = geo[k];
                if (gk.valid && y >= gk.y0 && y < gk.y0 + gk.ph &&
                    x >= gk.x0 && x < gk.x0 + gk.pw) { inc = false; break; }
            }
            if (inc) {
                float s[3];
                if (jph > 0) {
                    bsample_fast(patch, y - jy0, x - jx0, jphf, jpwf, s);
                } else {
                    const float* p = img + ((size_t)y * IMG_W + x) * 3;
                    s[0] = p[0]; s[1] = p[1]; s[2] = p[2];
                }
                v[0] += 1.f;
                v[1] += s[0]; v[2] += s[1]; v[3] += s[2];
                v[4] += s[0]*s[0]; v[5] += s[1]*s[1]; v[6] += s[2]*s[2];
            }
        }
        block_reduceN<7, 4>(v);
        if (tid == 0) {
#pragma unroll
            for (int k = 0; k < 7; ++k) o[k] = v[k];
        }
    }
}

// ---------------------------------------------------------------------------
// K3: per-image 16-step recurrence. One wave per image.
// ---------------------------------------------------------------------------
__global__ void solve_coeffs(const float* __restrict__ boxes,
                             float* __restrict__ ws) {
    const int b = blockIdx.x;
    const int lane = threadIdx.x;       // 64 threads = 1 wave

    BoxGeo g = make_geo(boxes + (b * NBOX + (lane < NBOX ? lane : NBOX - 1)) * 4);
    float pm[3], ps[3];
#pragma unroll
    for (int c = 0; c < 3; ++c) { pm[c] = ws[WS_PMEAN + c]; ps[c] = ws[WS_PSTD + c]; }

    float sc[3] = {0.f, 0.f, 0.f}, of[3] = {0.f, 0.f, 0.f};

    for (int i = 0; i < NBOX; ++i) {
        const int valid_i = __shfl(g.valid, i, 64);
        if (!valid_i) continue;

        float cnt = 0.f, s1[3] = {0.f,0.f,0.f}, s2[3] = {0.f,0.f,0.f};
        if (lane <= i) {
            const int slot0 = (lane == 0) ? 0 : (Z0 + lane - 1);
            const int nz = (lane == 0) ? Z0 : 1;
            const float* p = ws + WS_PAIR +
                ((size_t)(b * NBOX + i) * SLOTS + slot0) * 8;
            for (int zz = 0; zz < nz; ++zz) {
                cnt   += p[zz*8 + 0];
                s1[0] += p[zz*8 + 1]; s1[1] += p[zz*8 + 2]; s1[2] += p[zz*8 + 3];
                s2[0] += p[zz*8 + 4]; s2[1] += p[zz*8 + 5]; s2[2] += p[zz*8 + 6];
            }
        }
        float ts[3], tq[3];
#pragma unroll
        for (int c = 0; c < 3; ++c) {
            if (lane == 0) { ts[c] = s1[c]; tq[c] = s2[c]; }
            else {
                ts[c] = sc[c] * s1[c] + of[c] * cnt;
                tq[c] = sc[c]*sc[c]*s2[c] + 2.f*sc[c]*of[c]*s1[c] + of[c]*of[c]*cnt;
            }
        }
#pragma unroll
        for (int c = 0; c < 3; ++c) {
#pragma unroll
            for (int off = 16; off > 0; off >>= 1) {
                ts[c] += __shfl_down(ts[c], off, 32);
                tq[c] += __shfl_down(tq[c], off, 32);
            }
        }
        const int phi = __shfl(g.ph, i, 64);
        const int pwi = __shfl(g.pw, i, 64);
        const float cntf = fmaxf((float)(phi * pwi), 1.0f);
        float nsc[3] = {0.f,0.f,0.f}, nof[3] = {0.f,0.f,0.f};
        if (lane == 0) {
#pragma unroll
            for (int c = 0; c < 3; ++c) {
                float mean = ts[c] / cntf;
                float var = tq[c] / cntf - mean * mean;
                float sd = sqrtf(fmaxf(var, 0.f)) + 1e-6f;
                nsc[c] = sd / ps[c];
                nof[c] = mean - pm[c] * nsc[c];
            }
        }
#pragma unroll
        for (int c = 0; c < 3; ++c) {
            float bs = __shfl(nsc[c], 0, 64);
            float bo = __shfl(nof[c], 0, 64);
            if (lane == i + 1) { sc[c] = bs; of[c] = bo; }
            if (lane == 0) {
                ws[WS_COEF + (size_t)(b * NBOX + i) * 8 + c] = bs;
                ws[WS_COEF + (size_t)(b * NBOX + i) * 8 + 3 + c] = bo;
            }
        }
    }
}

// ---------------------------------------------------------------------------
// K4: decal — overwrite exclusive last-coverer regions only (copy done in K2).
// ---------------------------------------------------------------------------
__launch_bounds__(256)
__global__ void decal(const float* __restrict__ boxes,
                      const float* __restrict__ patch,
                      const float* __restrict__ ws,
                      float* __restrict__ out) {
    const int bi = blockIdx.x;
    const int b = bi >> 4, i = bi & 15;
    const int z = blockIdx.y;                   // 0..7
    __shared__ BoxGeo geo[NBOX];
    __shared__ float coef[6];
    if (threadIdx.x < NBOX)
        geo[threadIdx.x] = make_geo(boxes + (b * NBOX + threadIdx.x) * 4);
    if (threadIdx.x >= 32 && threadIdx.x < 38)
        coef[threadIdx.x - 32] = ws[WS_COEF + (size_t)bi * 8 + (threadIdx.x - 32)];
    __syncthreads();
    const BoxGeo gi = geo[i];
    if (!gi.valid) return;
    const int y0 = gi.y0, x0 = gi.x0, ph = gi.ph, pw = gi.pw;
    const int n = ph * pw;
    const float phf = (float)ph, pwf = (float)pw;
    float* img = out + (size_t)b * IMG_H * IMG_W * 3;

    for (int t = z * 256 + threadIdx.x; t < n; t += 256 * 8) {
        const int y = y0 + t / pw;
        const int x = x0 + t % pw;
        bool cov = false;
        for (int k = i + 1; k < NBOX; ++k) {
            const BoxGeo g = geo[k];
            if (g.valid && y >= g.y0 && y < g.y0 + g.ph &&
                x >= g.x0 && x < g.x0 + g.pw) { cov = true; break; }
        }
        if (!cov) {
            float s[3];
            bsample_fast(patch, y - y0, x - x0, phf, pwf, s);
            float* o = img + ((size_t)y * IMG_W + x) * 3;
            o[0] = s[0] * coef[0] + coef[3];
            o[1] = s[1] * coef[1] + coef[4];
            o[2] = s[2] * coef[2] + coef[5];
        }
    }
}

extern "C" void kernel_launch(void* const* d_in, const int* in_sizes, int n_in,
                              void* d_out, int out_size, void* d_ws, size_t ws_size,
                              hipStream_t stream) {
    const float* images = (const float*)d_in[0];
    const float* boxes  = (const float*)d_in[1];
    const float* patch  = (const float*)d_in[2];
    float* out = (float*)d_out;
    float* ws  = (float*)d_ws;

    patch_stats_partial<<<256, 256, 0, stream>>>(patch, ws);
    fused<<<FBLOCKS, 256, 0, stream>>>(images, boxes, patch, ws, out);
    solve_coeffs<<<NIMG, 64, 0, stream>>>(boxes, ws);
    decal<<<dim3(NIMG * NBOX, 8), 256, 0, stream>>>(boxes, patch, ws, out);
}

// Round 17
// 101.869 us; speedup vs baseline: 1.1471x; 1.1471x over previous
//
#include <hip/hip_runtime.h>
#include <math.h>

#define IMG_H 512
#define IMG_W 512
#define PSIZE 512
#define NIMG 16
#define NBOX 16
#define Z0 8                    // z-split for j==-1 full-rect tasks
#define SLOTS 24                // Z0 + 15 pair slots (j=0..14) per (b,i)
#define IT_J0   256             // items [0,256) = stats partials
#define IT_PAIR 2304            // [256,2304) = j0 tasks (bi*8+z)
#define IT_COPY 4224            // [2304,4224) = pairs (b*120+p)
#define NITEMS  6272            // [4224,6272) = copy chunks
#define FBLOCKS 4096
#define CHUNK4  1536            // float4 per copy chunk (6/thread)

// workspace layout (floats)
#define WS_PART 0               // 256*6
#define WS_PAIR 1536            // [bi][SLOTS][8]

typedef float f4u __attribute__((ext_vector_type(4), aligned(4)));
typedef float f2u __attribute__((ext_vector_type(2), aligned(4)));

struct BoxGeo { int y0, x0, ph, pw, valid; };

__device__ __forceinline__ BoxGeo make_geo(const float* bx) {
    float ymin = bx[0], xmin = bx[1], ymax = bx[2], xmax = bx[3];
    float h = ymax - ymin, w = xmax - xmin;
    float pwf = h * 0.3f;            // SCALE
    float phf = 1.0f * pwf;          // ASPECT * pw
    float oy = ymin + h * 0.5f;
    float ox = xmin + w * 0.5f;
    float yp = fmaxf(oy - phf * 0.5f, 0.0f);
    float xp = fmaxf(ox - pwf * 0.5f, 0.0f);
    if (yp + phf > (float)IMG_H) yp = (float)IMG_H - phf;
    if (xp + pwf > (float)IMG_W) xp = (float)IMG_W - pwf;
    BoxGeo g;
    g.y0 = (int)yp; g.x0 = (int)xp;   // tf.cast truncation
    g.ph = (int)phf; g.pw = (int)pwf;
    g.valid = (phf > 60.0f) ? 1 : 0;  // MIN_PATCH_H tested on float ph
    return g;
}

// vectorized bilinear: 4 memory requests (dwordx4 + dwordx2 per row).
__device__ __forceinline__ void bsample_fast(const float* __restrict__ patch,
                                             int relY, int relX,
                                             float phf, float pwf, float s[3]) {
    float sy = ((float)relY + 0.5f) * (float)PSIZE / phf - 0.5f;
    sy = fminf(fmaxf(sy, 0.0f), (float)(PSIZE - 1));
    float sx = ((float)relX + 0.5f) * (float)PSIZE / pwf - 0.5f;
    sx = fminf(fmaxf(sx, 0.0f), (float)(PSIZE - 1));
    int y0 = (int)floorf(sy);
    int y1 = min(y0 + 1, PSIZE - 1);
    int x0 = (int)floorf(sx);
    float wy = sy - (float)y0;
    float wx = sx - (float)x0;
    const int baseX = min(x0, PSIZE - 2);
    const bool hi = (x0 == PSIZE - 1);          // then wx == 0
    const float* r0 = patch + (y0 * PSIZE + baseX) * 3;
    const float* r1 = patch + (y1 * PSIZE + baseX) * 3;
    f4u a0 = *(const f4u*)r0; f2u b0 = *(const f2u*)(r0 + 4);
    f4u a1 = *(const f4u*)r1; f2u b1 = *(const f2u*)(r1 + 4);
    float p00, p01, p10, p11, top, bot;
    p00 = hi ? a0.w : a0.x;  p01 = a0.w;
    p10 = hi ? a1.w : a1.x;  p11 = a1.w;
    top = (1.f - wx) * p00 + wx * p01; bot = (1.f - wx) * p10 + wx * p11;
    s[0] = (1.f - wy) * top + wy * bot;
    p00 = hi ? b0.x : a0.y;  p01 = b0.x;
    p10 = hi ? b1.x : a1.y;  p11 = b1.x;
    top = (1.f - wx) * p00 + wx * p01; bot = (1.f - wx) * p10 + wx * p11;
    s[1] = (1.f - wy) * top + wy * bot;
    p00 = hi ? b0.y : a0.z;  p01 = b0.y;
    p10 = hi ? b1.y : a1.z;  p11 = b1.y;
    top = (1.f - wx) * p00 + wx * p01; bot = (1.f - wx) * p10 + wx * p11;
    s[2] = (1.f - wy) * top + wy * bot;
}

template<int N, int NWAVES>
__device__ __forceinline__ void block_reduceN(float v[N]) {
    __shared__ float lds[NWAVES][N];
    const int lane = threadIdx.x & 63;
    const int wave = threadIdx.x >> 6;
    __syncthreads();
#pragma unroll
    for (int k = 0; k < N; ++k) {
#pragma unroll
        for (int off = 32; off > 0; off >>= 1)
            v[k] += __shfl_down(v[k], off, 64);
    }
    if (lane == 0) {
#pragma unroll
        for (int k = 0; k < N; ++k) lds[wave][k] = v[k];
    }
    __syncthreads();
    if (wave == 0) {
#pragma unroll
        for (int k = 0; k < N; ++k) {
            float x = (lane < NWAVES) ? lds[lane][k] : 0.0f;
#pragma unroll
            for (int off = 32; off > 0; off >>= 1)
                x += __shfl_down(x, off, 64);
            if (lane == 0) lds[0][k] = x;
        }
    }
    __syncthreads();
#pragma unroll
    for (int k = 0; k < N; ++k) v[k] = lds[0][k];
}

// ===========================================================================
// K1: fused — grid-stride over [stats partials | j0 tasks | tri pairs | copy]
// ===========================================================================
__launch_bounds__(256)
__global__ void fused1(const float* __restrict__ images,
                       const float* __restrict__ boxes,
                       const float* __restrict__ patch,
                       float* __restrict__ ws,
                       float* __restrict__ out) {
    const int tid = threadIdx.x;
    __shared__ BoxGeo geo[NBOX];

    for (int it = blockIdx.x; it < NITEMS; it += FBLOCKS) {
        if (it < IT_J0) {                        // ---- stats partial ----
            const int g = it * 256 + tid;
            const float4* p4 = (const float4*)patch;
            float4 a = p4[3 * g], b = p4[3 * g + 1], c = p4[3 * g + 2];
            float v[6];
            v[0] = a.x + a.w + b.z + c.y;
            v[1] = a.y + b.x + b.w + c.z;
            v[2] = a.z + b.y + c.x + c.w;
            v[3] = a.x*a.x + a.w*a.w + b.z*b.z + c.y*c.y;
            v[4] = a.y*a.y + b.x*b.x + b.w*b.w + c.z*c.z;
            v[5] = a.z*a.z + b.y*b.y + c.x*c.x + c.w*c.w;
            block_reduceN<6, 4>(v);
            if (tid == 0) {
                float* o = ws + WS_PART + it * 6;
#pragma unroll
                for (int k = 0; k < 6; ++k) o[k] = v[k];
            }
            continue;
        }
        if (it >= IT_COPY) {                     // ---- copy chunk ----
            const int c = it - IT_COPY;
            const float4* s4 = (const float4*)images;
            float4* d4 = (float4*)out;
            const int base = c * CHUNK4 + tid;
#pragma unroll
            for (int u = 0; u < 6; ++u)
                d4[base + u * 256] = s4[base + u * 256];
            continue;
        }
        // ---- pair-sum task ----
        int b, i, j, z;
        if (it < IT_PAIR) {                      // j = -1 (original image)
            const int idx = it - IT_J0;
            const int bi = idx >> 3; z = idx & 7;
            b = bi >> 4; i = bi & 15; j = -1;
        } else {                                 // triangular (i,j), j < i
            const int idx = it - IT_PAIR;
            b = idx / 120;
            int p = idx % 120;
            int pi = 1, t = p;
            while (t >= pi) { t -= pi; ++pi; }
            i = pi; j = t; z = 0;
        }
        const BoxGeo gi = make_geo(boxes + (b * NBOX + i) * 4);
        if (!gi.valid) continue;                 // solve skips invalid i

        const int slot = (j < 0) ? z : (Z0 + j);
        float* o = ws + WS_PAIR + ((size_t)(b * NBOX + i) * SLOTS + slot) * 8;

        int ry0 = gi.y0, rx0 = gi.x0;
        int ry1 = gi.y0 + gi.ph, rx1 = gi.x0 + gi.pw;
        int jy0 = 0, jx0 = 0, jph = -1;
        float jphf = 1.f, jpwf = 1.f;
        if (j >= 0) {
            const BoxGeo gj = make_geo(boxes + (b * NBOX + j) * 4);
            if (!gj.valid) {
                if (tid == 0) { for (int k = 0; k < 7; ++k) o[k] = 0.f; }
                continue;
            }
            ry0 = max(ry0, gj.y0); rx0 = max(rx0, gj.x0);
            ry1 = min(ry1, gj.y0 + gj.ph); rx1 = min(rx1, gj.x0 + gj.pw);
            jy0 = gj.y0; jx0 = gj.x0; jph = gj.ph;
            jphf = (float)gj.ph; jpwf = (float)gj.pw;
        }
        const int rw = rx1 - rx0, rh = ry1 - ry0;
        if (rw <= 0 || rh <= 0) {
            if (tid == 0) { for (int k = 0; k < 7; ++k) o[k] = 0.f; }
            continue;
        }

        __syncthreads();                         // guard geo[] reuse
        if (tid < NBOX)
            geo[tid] = make_geo(boxes + (b * NBOX + tid) * 4);
        __syncthreads();

        const int n = rw * rh;
        const float* img = images + (size_t)b * IMG_H * IMG_W * 3;
        const int stride = (j < 0) ? 256 * Z0 : 256;

        float v[7] = {0.f, 0.f, 0.f, 0.f, 0.f, 0.f, 0.f};
        for (int t = ((j < 0) ? z * 256 : 0) + tid; t < n; t += stride) {
            const int y = ry0 + t / rw;
            const int x = rx0 + t % rw;
            bool inc = true;
            for (int k = j + 1; k < i; ++k) {
                const BoxGeo gk = geo[k];
                if (gk.valid && y >= gk.y0 && y < gk.y0 + gk.ph &&
                    x >= gk.x0 && x < gk.x0 + gk.pw) { inc = false; break; }
            }
            if (inc) {
                float s[3];
                if (jph > 0) {
                    bsample_fast(patch, y - jy0, x - jx0, jphf, jpwf, s);
                } else {
                    const float* p = img + ((size_t)y * IMG_W + x) * 3;
                    s[0] = p[0]; s[1] = p[1]; s[2] = p[2];
                }
                v[0] += 1.f;
                v[1] += s[0]; v[2] += s[1]; v[3] += s[2];
                v[4] += s[0]*s[0]; v[5] += s[1]*s[1]; v[6] += s[2]*s[2];
            }
        }
        block_reduceN<7, 4>(v);
        if (tid == 0) {
#pragma unroll
            for (int k = 0; k < 7; ++k) o[k] = v[k];
        }
    }
}

// ===========================================================================
// K2: solve+decal — block (bi, z). Wave 0 recomputes stats-final + the
// recurrence up to i (deterministic, identical in every block), then the
// block decals its exclusive last-coverer region.
// ===========================================================================
__launch_bounds__(256)
__global__ void solve_decal(const float* __restrict__ boxes,
                            const float* __restrict__ patch,
                            const float* __restrict__ ws,
                            float* __restrict__ out) {
    const int bi = blockIdx.x;
    const int z = blockIdx.y;
    const int b = bi >> 4, i = bi & 15;
    const int tid = threadIdx.x;
    __shared__ BoxGeo geo[NBOX];
    __shared__ float scoef[6];

    if (tid < NBOX)
        geo[tid] = make_geo(boxes + (b * NBOX + tid) * 4);
    __syncthreads();
    if (!geo[i].valid) return;                   // uniform

    if (tid < 64) {
        const int lane = tid;
        // stats final (butterfly — all lanes get the sums)
        float v[6] = {0.f, 0.f, 0.f, 0.f, 0.f, 0.f};
        for (int q = lane; q < 256; q += 64) {
            const float* p = ws + WS_PART + q * 6;
#pragma unroll
            for (int k = 0; k < 6; ++k) v[k] += p[k];
        }
#pragma unroll
        for (int k = 0; k < 6; ++k)
#pragma unroll
            for (int off = 32; off > 0; off >>= 1)
                v[k] += __shfl_xor(v[k], off, 64);
        const float n = (float)(PSIZE * PSIZE);
        float pm[3], ps[3];
#pragma unroll
        for (int c = 0; c < 3; ++c) {
            pm[c] = v[c] / n;
            ps[c] = sqrtf(fmaxf(v[3 + c] / n - pm[c] * pm[c], 0.f)) + 1e-6f;
        }

        BoxGeo g = geo[lane & 15];
        float sc[3] = {0.f, 0.f, 0.f}, of[3] = {0.f, 0.f, 0.f};

        for (int ii = 0; ii <= i; ++ii) {
            const int valid_i = __shfl(g.valid, ii, 64);
            if (!valid_i) continue;

            float cnt = 0.f, s1[3] = {0.f,0.f,0.f}, s2[3] = {0.f,0.f,0.f};
            if (lane <= ii) {
                const int slot0 = (lane == 0) ? 0 : (Z0 + lane - 1);
                const int nzz = (lane == 0) ? Z0 : 1;
                const float* p = ws + WS_PAIR +
                    ((size_t)(b * NBOX + ii) * SLOTS + slot0) * 8;
                for (int zz = 0; zz < nzz; ++zz) {
                    cnt   += p[zz*8 + 0];
                    s1[0] += p[zz*8 + 1]; s1[1] += p[zz*8 + 2]; s1[2] += p[zz*8 + 3];
                    s2[0] += p[zz*8 + 4]; s2[1] += p[zz*8 + 5]; s2[2] += p[zz*8 + 6];
                }
            }
            float ts[3], tq[3];
#pragma unroll
            for (int c = 0; c < 3; ++c) {
                if (lane == 0) { ts[c] = s1[c]; tq[c] = s2[c]; }
                else {
                    ts[c] = sc[c] * s1[c] + of[c] * cnt;
                    tq[c] = sc[c]*sc[c]*s2[c] + 2.f*sc[c]*of[c]*s1[c]
                          + of[c]*of[c]*cnt;
                }
            }
#pragma unroll
            for (int c = 0; c < 3; ++c) {
#pragma unroll
                for (int off = 16; off > 0; off >>= 1) {
                    ts[c] += __shfl_down(ts[c], off, 32);
                    tq[c] += __shfl_down(tq[c], off, 32);
                }
            }
            const int phi = __shfl(g.ph, ii, 64);
            const int pwi = __shfl(g.pw, ii, 64);
            const float cntf = fmaxf((float)(phi * pwi), 1.0f);
            float nsc[3] = {0.f,0.f,0.f}, nof[3] = {0.f,0.f,0.f};
            if (lane == 0) {
#pragma unroll
                for (int c = 0; c < 3; ++c) {
                    float mean = ts[c] / cntf;
                    float var = tq[c] / cntf - mean * mean;
                    float sd = sqrtf(fmaxf(var, 0.f)) + 1e-6f;
                    nsc[c] = sd / ps[c];
                    nof[c] = mean - pm[c] * nsc[c];
                }
            }
#pragma unroll
            for (int c = 0; c < 3; ++c) {
                float bs = __shfl(nsc[c], 0, 64);
                float bo = __shfl(nof[c], 0, 64);
                if (lane == ii + 1) { sc[c] = bs; of[c] = bo; }
                if (ii == i && lane == 0) { scoef[c] = bs; scoef[3 + c] = bo; }
            }
        }
    }
    __syncthreads();

    // decal this block's z-slice of rect_i's exclusive region
    const BoxGeo gi = geo[i];
    const int y0 = gi.y0, x0 = gi.x0, ph = gi.ph, pw = gi.pw;
    const int n = ph * pw;
    const float phf = (float)ph, pwf = (float)pw;
    float* img = out + (size_t)b * IMG_H * IMG_W * 3;

    for (int t = z * 256 + tid; t < n; t += 256 * 8) {
        const int y = y0 + t / pw;
        const int x = x0 + t % pw;
        bool cov = false;
        for (int k = i + 1; k < NBOX; ++k) {
            const BoxGeo g = geo[k];
            if (g.valid && y >= g.y0 && y < g.y0 + g.ph &&
                x >= g.x0 && x < g.x0 + g.pw) { cov = true; break; }
        }
        if (!cov) {
            float s[3];
            bsample_fast(patch, y - y0, x - x0, phf, pwf, s);
            float* o = img + ((size_t)y * IMG_W + x) * 3;
            o[0] = s[0] * scoef[0] + scoef[3];
            o[1] = s[1] * scoef[1] + scoef[4];
            o[2] = s[2] * scoef[2] + scoef[5];
        }
    }
}

extern "C" void kernel_launch(void* const* d_in, const int* in_sizes, int n_in,
                              void* d_out, int out_size, void* d_ws, size_t ws_size,
                              hipStream_t stream) {
    const float* images = (const float*)d_in[0];
    const float* boxes  = (const float*)d_in[1];
    const float* patch  = (const float*)d_in[2];
    float* out = (float*)d_out;
    float* ws  = (float*)d_ws;

    fused1<<<FBLOCKS, 256, 0, stream>>>(images, boxes, patch, ws, out);
    solve_decal<<<dim3(NIMG * NBOX, 8), 256, 0, stream>>>(boxes, patch, ws, out);
}